// Round 1
// baseline (183.785 us; speedup 1.0000x reference)
//
#include <hip/hip_runtime.h>

// AdaPT_Linear: per-tensor int8 quantized linear.
// out = (qx @ qw^T).f32 / (sa*sw) + qb.f32/sb
// x: [16384,1024] f32, w: [1024,1024] f32, b: [1024] f32, out: [16384,1024] f32

#define M_ROWS 16384
#define K_DIM  1024
#define N_OUT  1024

typedef int v4i __attribute__((ext_vector_type(4)));

__device__ __forceinline__ void gload_lds16(const void* g, void* l) {
  __builtin_amdgcn_global_load_lds(
      (const __attribute__((address_space(1))) void*)g,
      (__attribute__((address_space(3))) void*)l, 16, 0, 0);
}

__global__ void init_kernel(unsigned int* amax) {
  if (threadIdx.x < 4) amax[threadIdx.x] = 0u;
}

// global max(|t|) -> atomicMax on float bits (valid: abs values >= 0)
__global__ void amax_kernel(const float* __restrict__ src, int n4,
                            unsigned int* __restrict__ out) {
  int stride = gridDim.x * blockDim.x;
  float m = 0.0f;
  for (int idx = blockIdx.x * blockDim.x + threadIdx.x; idx < n4; idx += stride) {
    float4 v = ((const float4*)src)[idx];
    m = fmaxf(m, fmaxf(fmaxf(fabsf(v.x), fabsf(v.y)), fmaxf(fabsf(v.z), fabsf(v.w))));
  }
#pragma unroll
  for (int off = 32; off > 0; off >>= 1)
    m = fmaxf(m, __shfl_down(m, off));
  if ((threadIdx.x & 63) == 0)
    atomicMax(out, __float_as_uint(m));
}

// q = clamp(rint(scale * t), -127, 127) as int8, packed 4-wide
__global__ void quant_kernel(const float* __restrict__ src, signed char* __restrict__ dst,
                             int n4, const unsigned int* __restrict__ amax, int slot) {
  float t = __uint_as_float(amax[slot]);
  if (t == 0.0f) t = 1.0f;
  const float s = 127.0f / t;
  int stride = gridDim.x * blockDim.x;
  for (int idx = blockIdx.x * blockDim.x + threadIdx.x; idx < n4; idx += stride) {
    float4 v = ((const float4*)src)[idx];
    int q0 = (int)fminf(fmaxf(rintf(s * v.x), -127.0f), 127.0f);
    int q1 = (int)fminf(fmaxf(rintf(s * v.y), -127.0f), 127.0f);
    int q2 = (int)fminf(fmaxf(rintf(s * v.z), -127.0f), 127.0f);
    int q3 = (int)fminf(fmaxf(rintf(s * v.w), -127.0f), 127.0f);
    unsigned int packed = (q0 & 0xff) | ((q1 & 0xff) << 8) |
                          ((q2 & 0xff) << 16) | ((q3 & 0xff) << 24);
    ((unsigned int*)dst)[idx] = packed;
  }
}

// bdeq[j] = clamp(rint(sb*b[j]))/sb
__global__ void bias_kernel(const float* __restrict__ bias, float* __restrict__ bdeq,
                            const unsigned int* __restrict__ amax) {
  float t = __uint_as_float(amax[2]);
  if (t == 0.0f) t = 1.0f;
  const float sb = 127.0f / t;
  int j = blockIdx.x * blockDim.x + threadIdx.x;
  if (j < N_OUT) {
    float q = fminf(fmaxf(rintf(sb * bias[j]), -127.0f), 127.0f);
    bdeq[j] = q / sb;
  }
}

// i8 GEMM: C[m][n] = sum_k qx[m][k]*qw[n][k], 128x128 tile, BK=64, 4 waves.
#define TILE_M 128
#define TILE_N 128
#define TILE_K 64

__global__ __launch_bounds__(256) void gemm_kernel(
    const signed char* __restrict__ qx, const signed char* __restrict__ qw,
    const unsigned int* __restrict__ amax, const float* __restrict__ bdeq,
    float* __restrict__ out) {
  __shared__ signed char As[TILE_M * TILE_K];  // 8 KB
  __shared__ signed char Bs[TILE_N * TILE_K];  // 8 KB

  const int tid  = threadIdx.x;
  const int wid  = tid >> 6;
  const int lane = tid & 63;

  const int bm = blockIdx.x >> 3;  // 128 row-tiles
  const int bn = blockIdx.x & 7;   // 8 col-tiles
  const int brow = bm * TILE_M;
  const int bcol = bn * TILE_N;

  const int wm = wid >> 1;  // 0..1
  const int wn = wid & 1;   // 0..1

  float ax = __uint_as_float(amax[0]); if (ax == 0.0f) ax = 1.0f;
  float aw = __uint_as_float(amax[1]); if (aw == 0.0f) aw = 1.0f;
  const float sa = 127.0f / ax;
  const float sw = 127.0f / aw;
  const float denom = sa * sw;

  v4i acc[4][4] = {};

  // staging: chunk = 16 rows x 64B = 1024B (one wave-load of 16B/lane)
  const int srow  = lane >> 2;         // row within chunk
  const int sbyte = (lane & 3) << 4;   // 0,16,32,48

  for (int kt = 0; kt < K_DIM / TILE_K; ++kt) {
    if (kt) __syncthreads();
    const int k0 = kt * TILE_K;
#pragma unroll
    for (int i = 0; i < 2; ++i) {
      const int c = wid * 2 + i;  // chunk 0..7
      const signed char* ga = qx + (size_t)(brow + c * 16 + srow) * K_DIM + k0 + sbyte;
      gload_lds16(ga, &As[c * 1024]);
      const signed char* gb = qw + (size_t)(bcol + c * 16 + srow) * K_DIM + k0 + sbyte;
      gload_lds16(gb, &Bs[c * 1024]);
    }
    __syncthreads();

    v4i a[4], b[4];
    const int fr = lane & 15;
    const int kb = (lane >> 4) << 4;  // 16-byte k-chunk per lane group
#pragma unroll
    for (int t = 0; t < 4; ++t) {
      a[t] = *(const v4i*)(&As[(wm * 64 + t * 16 + fr) * TILE_K + kb]);
      b[t] = *(const v4i*)(&Bs[(wn * 64 + t * 16 + fr) * TILE_K + kb]);
    }
#pragma unroll
    for (int ti = 0; ti < 4; ++ti)
#pragma unroll
      for (int tj = 0; tj < 4; ++tj)
        acc[ti][tj] = __builtin_amdgcn_mfma_i32_16x16x64_i8(a[ti], b[tj], acc[ti][tj], 0, 0, 0);
  }

  // epilogue: D frag: col = lane&15, row = (lane>>4)*4 + i
#pragma unroll
  for (int ti = 0; ti < 4; ++ti) {
    const int row0 = brow + wm * 64 + ti * 16 + ((lane >> 4) << 2);
#pragma unroll
    for (int tj = 0; tj < 4; ++tj) {
      const int col = bcol + wn * 64 + tj * 16 + (lane & 15);
      const float bb = bdeq[col];
#pragma unroll
      for (int i = 0; i < 4; ++i) {
        out[(size_t)(row0 + i) * N_OUT + col] = (float)acc[ti][tj][i] / denom + bb;
      }
    }
  }
}

extern "C" void kernel_launch(void* const* d_in, const int* in_sizes, int n_in,
                              void* d_out, int out_size, void* d_ws, size_t ws_size,
                              hipStream_t stream) {
  const float* x = (const float*)d_in[0];
  const float* w = (const float*)d_in[1];
  const float* b = (const float*)d_in[2];
  float* out = (float*)d_out;

  char* ws = (char*)d_ws;
  unsigned int* amax = (unsigned int*)ws;               // 4 uints
  float* bdeq = (float*)(ws + 256);                     // 4 KB
  signed char* qw = (signed char*)(ws + 8192);          // 1 MB
  signed char* qx = (signed char*)(ws + (1 << 21));     // 16 MB

  hipLaunchKernelGGL(init_kernel, dim3(1), dim3(64), 0, stream, amax);
  hipLaunchKernelGGL(amax_kernel, dim3(2048), dim3(256), 0, stream, x, M_ROWS * K_DIM / 4, amax + 0);
  hipLaunchKernelGGL(amax_kernel, dim3(256), dim3(256), 0, stream, w, N_OUT * K_DIM / 4, amax + 1);
  hipLaunchKernelGGL(amax_kernel, dim3(4), dim3(256), 0, stream, b, N_OUT / 4, amax + 2);
  hipLaunchKernelGGL(quant_kernel, dim3(2048), dim3(256), 0, stream, x, qx, M_ROWS * K_DIM / 4, amax, 0);
  hipLaunchKernelGGL(quant_kernel, dim3(256), dim3(256), 0, stream, w, qw, N_OUT * K_DIM / 4, amax, 1);
  hipLaunchKernelGGL(bias_kernel, dim3(4), dim3(256), 0, stream, b, bdeq, amax);
  hipLaunchKernelGGL(gemm_kernel, dim3(128 * 8), dim3(256), 0, stream, qx, qw, amax, bdeq, out);
}

// Round 2
// 79.346 us; speedup vs baseline: 2.3163x; 2.3163x over previous
//
#include <hip/hip_runtime.h>

// AdaPT_Linear: per-tensor int8 quantized linear.
// out = (qx @ qw^T).f32 / (sa*sw) + qb.f32/sb
// x: [16384,1024] f32, w: [1024,1024] f32, b: [1024] f32, out: [16384,1024] f32

#define M_ROWS 16384
#define K_DIM  1024
#define N_OUT  1024

typedef int v4i __attribute__((ext_vector_type(4)));

__device__ __forceinline__ void gload_lds16(const void* g, void* l) {
  __builtin_amdgcn_global_load_lds(
      (const __attribute__((address_space(1))) void*)g,
      (__attribute__((address_space(3))) void*)l, 16, 0, 0);
}

__device__ __forceinline__ float block_reduce_max4(float m, float* red) {
  // 4 waves / 256 threads assumed
#pragma unroll
  for (int off = 32; off > 0; off >>= 1)
    m = fmaxf(m, __shfl_down(m, off));
  const int wid = threadIdx.x >> 6, lane = threadIdx.x & 63;
  if (lane == 0) red[wid] = m;
  __syncthreads();
  float r = fmaxf(fmaxf(red[0], red[1]), fmaxf(red[2], red[3]));
  __syncthreads();
  return r;
}

// stage 1: per-block max(|src|) -> partials[block]  (no atomics)
__global__ void amax_stage1(const float* __restrict__ src, int n4,
                            float* __restrict__ partials) {
  __shared__ float red[4];
  float m = 0.0f;
  const int stride = gridDim.x * blockDim.x;
  for (int idx = blockIdx.x * blockDim.x + threadIdx.x; idx < n4; idx += stride) {
    float4 v = ((const float4*)src)[idx];
    m = fmaxf(m, fmaxf(fmaxf(fabsf(v.x), fabsf(v.y)), fmaxf(fabsf(v.z), fabsf(v.w))));
  }
  float r = block_reduce_max4(m, red);
  if (threadIdx.x == 0) partials[blockIdx.x] = r;
}

// stage 2 (1 block, 256 thr): reduce x/w partials, bias amax + dequant bias.
// amax[i] stores (t_max==0 ? 1 : t_max) so downstream just divides.
__global__ void finalize_kernel(const float* __restrict__ px, int npx,
                                const float* __restrict__ pw, int npw,
                                const float* __restrict__ bias,
                                float* __restrict__ amax,
                                float* __restrict__ bdeq) {
  __shared__ float red[4];
  const int tid = threadIdx.x;

  float m = 0.0f;
  for (int i = tid; i < npx; i += 256) m = fmaxf(m, px[i]);
  float rx = block_reduce_max4(m, red);

  m = 0.0f;
  for (int i = tid; i < npw; i += 256) m = fmaxf(m, pw[i]);
  float rw = block_reduce_max4(m, red);

  float4 bv = ((const float4*)bias)[tid];  // 256*4 == 1024 exactly
  m = fmaxf(fmaxf(fabsf(bv.x), fabsf(bv.y)), fmaxf(fabsf(bv.z), fabsf(bv.w)));
  float rb = block_reduce_max4(m, red);

  if (rx == 0.0f) rx = 1.0f;
  if (rw == 0.0f) rw = 1.0f;
  if (rb == 0.0f) rb = 1.0f;
  if (tid == 0) {
    amax[0] = rx;
    amax[1] = rw;
    amax[2] = rb;
  }
  // dequantized bias: clamp(rint(sb*b))/sb
  const float sb = 127.0f / rb;
  float4 q;
  q.x = fminf(fmaxf(rintf(sb * bv.x), -127.0f), 127.0f) / sb;
  q.y = fminf(fmaxf(rintf(sb * bv.y), -127.0f), 127.0f) / sb;
  q.z = fminf(fmaxf(rintf(sb * bv.z), -127.0f), 127.0f) / sb;
  q.w = fminf(fmaxf(rintf(sb * bv.w), -127.0f), 127.0f) / sb;
  ((float4*)bdeq)[tid] = q;
}

// q = clamp(rint(scale * t), -127, 127) as int8, packed 4-wide
__global__ void quant_kernel(const float* __restrict__ src, signed char* __restrict__ dst,
                             int n4, const float* __restrict__ amax, int slot) {
  const float s = 127.0f / amax[slot];
  const int stride = gridDim.x * blockDim.x;
  for (int idx = blockIdx.x * blockDim.x + threadIdx.x; idx < n4; idx += stride) {
    float4 v = ((const float4*)src)[idx];
    int q0 = (int)fminf(fmaxf(rintf(s * v.x), -127.0f), 127.0f);
    int q1 = (int)fminf(fmaxf(rintf(s * v.y), -127.0f), 127.0f);
    int q2 = (int)fminf(fmaxf(rintf(s * v.z), -127.0f), 127.0f);
    int q3 = (int)fminf(fmaxf(rintf(s * v.w), -127.0f), 127.0f);
    unsigned int packed = (q0 & 0xff) | ((q1 & 0xff) << 8) |
                          ((q2 & 0xff) << 16) | ((q3 & 0xff) << 24);
    ((unsigned int*)dst)[idx] = packed;
  }
}

// i8 GEMM: C[m][n] = sum_k qx[m][k]*qw[n][k], 128x128 tile, BK=64, 4 waves.
#define TILE_M 128
#define TILE_N 128
#define TILE_K 64

__global__ __launch_bounds__(256) void gemm_kernel(
    const signed char* __restrict__ qx, const signed char* __restrict__ qw,
    const float* __restrict__ amax, const float* __restrict__ bdeq,
    float* __restrict__ out) {
  __shared__ signed char As[TILE_M * TILE_K];  // 8 KB
  __shared__ signed char Bs[TILE_N * TILE_K];  // 8 KB

  const int tid  = threadIdx.x;
  const int wid  = tid >> 6;
  const int lane = tid & 63;

  const int bm = blockIdx.x >> 3;  // 128 row-tiles
  const int bn = blockIdx.x & 7;   // 8 col-tiles
  const int brow = bm * TILE_M;
  const int bcol = bn * TILE_N;

  const int wm = wid >> 1;  // 0..1
  const int wn = wid & 1;   // 0..1

  const float sa = 127.0f / amax[0];
  const float sw = 127.0f / amax[1];
  const float denom = sa * sw;

  v4i acc[4][4] = {};

  // staging: chunk = 16 rows x 64B = 1024B (one wave-load of 16B/lane)
  const int srow  = lane >> 2;         // row within chunk
  const int sbyte = (lane & 3) << 4;   // 0,16,32,48

  for (int kt = 0; kt < K_DIM / TILE_K; ++kt) {
    if (kt) __syncthreads();
    const int k0 = kt * TILE_K;
#pragma unroll
    for (int i = 0; i < 2; ++i) {
      const int c = wid * 2 + i;  // chunk 0..7
      const signed char* ga = qx + (size_t)(brow + c * 16 + srow) * K_DIM + k0 + sbyte;
      gload_lds16(ga, &As[c * 1024]);
      const signed char* gb = qw + (size_t)(bcol + c * 16 + srow) * K_DIM + k0 + sbyte;
      gload_lds16(gb, &Bs[c * 1024]);
    }
    __syncthreads();

    v4i a[4], b[4];
    const int fr = lane & 15;
    const int kb = (lane >> 4) << 4;  // 16-byte k-chunk per lane group
#pragma unroll
    for (int t = 0; t < 4; ++t) {
      a[t] = *(const v4i*)(&As[(wm * 64 + t * 16 + fr) * TILE_K + kb]);
      b[t] = *(const v4i*)(&Bs[(wn * 64 + t * 16 + fr) * TILE_K + kb]);
    }
#pragma unroll
    for (int ti = 0; ti < 4; ++ti)
#pragma unroll
      for (int tj = 0; tj < 4; ++tj)
        acc[ti][tj] = __builtin_amdgcn_mfma_i32_16x16x64_i8(a[ti], b[tj], acc[ti][tj], 0, 0, 0);
  }

  // epilogue: D frag: col = lane&15, row = (lane>>4)*4 + i
#pragma unroll
  for (int ti = 0; ti < 4; ++ti) {
    const int row0 = brow + wm * 64 + ti * 16 + ((lane >> 4) << 2);
#pragma unroll
    for (int tj = 0; tj < 4; ++tj) {
      const int col = bcol + wn * 64 + tj * 16 + (lane & 15);
      const float bb = bdeq[col];
#pragma unroll
      for (int i = 0; i < 4; ++i) {
        out[(size_t)(row0 + i) * N_OUT + col] = (float)acc[ti][tj][i] / denom + bb;
      }
    }
  }
}

extern "C" void kernel_launch(void* const* d_in, const int* in_sizes, int n_in,
                              void* d_out, int out_size, void* d_ws, size_t ws_size,
                              hipStream_t stream) {
  const float* x = (const float*)d_in[0];
  const float* w = (const float*)d_in[1];
  const float* b = (const float*)d_in[2];
  float* out = (float*)d_out;

  char* ws = (char*)d_ws;
  float* amax = (float*)ws;                             // 3 floats
  float* bdeq = (float*)(ws + 256);                     // 4 KB
  float* px   = (float*)(ws + 8192);                    // 2048 partials (8 KB)
  float* pw   = (float*)(ws + 16384 + 8192);            // 256 partials
  signed char* qw = (signed char*)(ws + 65536);         // 1 MB
  signed char* qx = (signed char*)(ws + (1 << 21));     // 16 MB

  const int NPX = 2048, NPW = 256;
  hipLaunchKernelGGL(amax_stage1, dim3(NPX), dim3(256), 0, stream, x, M_ROWS * K_DIM / 4, px);
  hipLaunchKernelGGL(amax_stage1, dim3(NPW), dim3(256), 0, stream, w, N_OUT * K_DIM / 4, pw);
  hipLaunchKernelGGL(finalize_kernel, dim3(1), dim3(256), 0, stream, px, NPX, pw, NPW, b, amax, bdeq);
  hipLaunchKernelGGL(quant_kernel, dim3(2048), dim3(256), 0, stream, x, qx, M_ROWS * K_DIM / 4, amax, 0);
  hipLaunchKernelGGL(quant_kernel, dim3(256), dim3(256), 0, stream, w, qw, N_OUT * K_DIM / 4, amax, 1);
  hipLaunchKernelGGL(gemm_kernel, dim3(128 * 8), dim3(256), 0, stream, qx, qw, amax, bdeq, out);
}

// Round 3
// 70.740 us; speedup vs baseline: 2.5980x; 1.1217x over previous
//
#include <hip/hip_runtime.h>

// AdaPT_Linear: per-tensor int8 quantized linear.
// out = (qx @ qw^T).f32 / (sa*sw) + qb.f32/sb
// x: [16384,1024] f32, w: [1024,1024] f32, b: [1024] f32, out: [16384,1024] f32

#define M_ROWS 16384
#define K_DIM  1024
#define N_OUT  1024

typedef int v4i __attribute__((ext_vector_type(4)));

__device__ __forceinline__ void gload_lds16(const void* g, void* l) {
  __builtin_amdgcn_global_load_lds(
      (const __attribute__((address_space(1))) void*)g,
      (__attribute__((address_space(3))) void*)l, 16, 0, 0);
}

__device__ __forceinline__ float block_reduce_max4(float m, float* red) {
  // 4 waves / 256 threads assumed
#pragma unroll
  for (int off = 32; off > 0; off >>= 1)
    m = fmaxf(m, __shfl_down(m, off));
  const int wid = threadIdx.x >> 6, lane = threadIdx.x & 63;
  if (lane == 0) red[wid] = m;
  __syncthreads();
  float r = fmaxf(fmaxf(red[0], red[1]), fmaxf(red[2], red[3]));
  __syncthreads();
  return r;
}

// stage 1: per-block max(|src|) -> partials[block]  (no atomics)
__global__ void amax_stage1(const float* __restrict__ src, int n4,
                            float* __restrict__ partials) {
  __shared__ float red[4];
  float m = 0.0f;
  const int stride = gridDim.x * blockDim.x;
  for (int idx = blockIdx.x * blockDim.x + threadIdx.x; idx < n4; idx += stride) {
    float4 v = ((const float4*)src)[idx];
    m = fmaxf(m, fmaxf(fmaxf(fabsf(v.x), fabsf(v.y)), fmaxf(fabsf(v.z), fabsf(v.w))));
  }
  float r = block_reduce_max4(m, red);
  if (threadIdx.x == 0) partials[blockIdx.x] = r;
}

// stage 2 (1 block, 256 thr): reduce x/w partials, bias amax + dequant bias.
// amax[i] stores (t_max==0 ? 1 : t_max) so downstream just divides.
__global__ void finalize_kernel(const float* __restrict__ px, int npx,
                                const float* __restrict__ pw, int npw,
                                const float* __restrict__ bias,
                                float* __restrict__ amax,
                                float* __restrict__ bdeq) {
  __shared__ float red[4];
  const int tid = threadIdx.x;

  float m = 0.0f;
  for (int i = tid; i < npx; i += 256) m = fmaxf(m, px[i]);
  float rx = block_reduce_max4(m, red);

  m = 0.0f;
  for (int i = tid; i < npw; i += 256) m = fmaxf(m, pw[i]);
  float rw = block_reduce_max4(m, red);

  float4 bv = ((const float4*)bias)[tid];  // 256*4 == 1024 exactly
  m = fmaxf(fmaxf(fabsf(bv.x), fabsf(bv.y)), fmaxf(fabsf(bv.z), fabsf(bv.w)));
  float rb = block_reduce_max4(m, red);

  if (rx == 0.0f) rx = 1.0f;
  if (rw == 0.0f) rw = 1.0f;
  if (rb == 0.0f) rb = 1.0f;
  if (tid == 0) {
    amax[0] = rx;
    amax[1] = rw;
    amax[2] = rb;
  }
  // dequantized bias: clamp(rint(sb*b))/sb
  const float sb = 127.0f / rb;
  float4 q;
  q.x = fminf(fmaxf(rintf(sb * bv.x), -127.0f), 127.0f) / sb;
  q.y = fminf(fmaxf(rintf(sb * bv.y), -127.0f), 127.0f) / sb;
  q.z = fminf(fmaxf(rintf(sb * bv.z), -127.0f), 127.0f) / sb;
  q.w = fminf(fmaxf(rintf(sb * bv.w), -127.0f), 127.0f) / sb;
  ((float4*)bdeq)[tid] = q;
}

// q = clamp(rint(scale * t), -127, 127) as int8, packed 4-wide
__global__ void quant_kernel(const float* __restrict__ src, signed char* __restrict__ dst,
                             int n4, const float* __restrict__ amax, int slot) {
  const float s = 127.0f / amax[slot];
  const int stride = gridDim.x * blockDim.x;
  for (int idx = blockIdx.x * blockDim.x + threadIdx.x; idx < n4; idx += stride) {
    float4 v = ((const float4*)src)[idx];
    int q0 = (int)fminf(fmaxf(rintf(s * v.x), -127.0f), 127.0f);
    int q1 = (int)fminf(fmaxf(rintf(s * v.y), -127.0f), 127.0f);
    int q2 = (int)fminf(fmaxf(rintf(s * v.z), -127.0f), 127.0f);
    int q3 = (int)fminf(fmaxf(rintf(s * v.w), -127.0f), 127.0f);
    unsigned int packed = (q0 & 0xff) | ((q1 & 0xff) << 8) |
                          ((q2 & 0xff) << 16) | ((q3 & 0xff) << 24);
    ((unsigned int*)dst)[idx] = packed;
  }
}

// i8 GEMM: C[m][n] = sum_k qx[m][k]*qw[n][k].
// 128x128 tile, BK=64, 4 waves, double-buffered LDS (2-phase),
// XOR k-column swizzle (pre-swizzled global src + swizzled ds_read).
#define TILE_M 128
#define TILE_N 128
#define TILE_K 64
#define NKT (K_DIM / TILE_K)

__global__ __launch_bounds__(256) void gemm_kernel(
    const signed char* __restrict__ qx, const signed char* __restrict__ qw,
    const float* __restrict__ amax, const float* __restrict__ bdeq,
    float* __restrict__ out) {
  __shared__ signed char As[2][TILE_M * TILE_K];  // 2 x 8 KB
  __shared__ signed char Bs[2][TILE_N * TILE_K];  // 2 x 8 KB

  const int tid  = threadIdx.x;
  const int wid  = tid >> 6;
  const int lane = tid & 63;

  // bijective XCD swizzle: grid 1024 = 8 xcds x 128 contiguous blocks
  const int wgid = (blockIdx.x & 7) * 128 + (blockIdx.x >> 3);
  const int bm = wgid >> 3;  // 128 row-tiles
  const int bn = wgid & 7;   // 8 col-tiles
  const int brow = bm * TILE_M;
  const int bcol = bn * TILE_N;

  const int wm = wid >> 1;  // 0..1
  const int wn = wid & 1;   // 0..1

  const float sa = 127.0f / amax[0];
  const float sw = 127.0f / amax[1];
  const float inv_denom = (amax[0] * amax[1]) * (1.0f / (127.0f * 127.0f));
  (void)sa; (void)sw;

  v4i acc[4][4] = {};

  // staging: chunk c = 16 rows x 64B; lane -> (row=lane>>2, col16=lane&3).
  // LDS slot (row, col16) holds global 16B column (col16 ^ (row&3)).
  const int srow = lane >> 2;
  const int scol = (((lane & 3) ^ (srow & 3)) << 4);
  const int c0 = wid * 2, c1 = wid * 2 + 1;
  const int r0 = c0 * 16 + srow, r1 = c1 * 16 + srow;
  const signed char* gA = qx + (size_t)(brow)*K_DIM;
  const signed char* gB = qw + (size_t)(bcol)*K_DIM;

#define STAGE(buf, kt)                                                   \
  do {                                                                   \
    const int _k0 = (kt)*TILE_K + scol;                                  \
    gload_lds16(gA + (size_t)r0 * K_DIM + _k0, &As[buf][c0 * 1024]);     \
    gload_lds16(gB + (size_t)r0 * K_DIM + _k0, &Bs[buf][c0 * 1024]);     \
    gload_lds16(gA + (size_t)r1 * K_DIM + _k0, &As[buf][c1 * 1024]);     \
    gload_lds16(gB + (size_t)r1 * K_DIM + _k0, &Bs[buf][c1 * 1024]);     \
  } while (0)

  // fragment read: row R = w*64 + t*16 + fr, k-chunk q=(lane>>4).
  // stored col16 = q ^ (R&3) = q ^ (fr&3)
  const int fr = lane & 15;
  const int kswz = (((lane >> 4) ^ (fr & 3)) << 4);

  int cur = 0;
  STAGE(0, 0);
  __syncthreads();  // compiler drains vmcnt(0) before s_barrier

  for (int kt = 0; kt < NKT; ++kt) {
    if (kt + 1 < NKT) STAGE(cur ^ 1, kt + 1);

    v4i a[4], b[4];
    const signed char* pa = &As[cur][(wm * 64 + fr) * TILE_K + kswz];
    const signed char* pb = &Bs[cur][(wn * 64 + fr) * TILE_K + kswz];
#pragma unroll
    for (int t = 0; t < 4; ++t) {
      a[t] = *(const v4i*)(pa + t * 16 * TILE_K);
      b[t] = *(const v4i*)(pb + t * 16 * TILE_K);
    }
#pragma unroll
    for (int ti = 0; ti < 4; ++ti)
#pragma unroll
      for (int tj = 0; tj < 4; ++tj)
        acc[ti][tj] = __builtin_amdgcn_mfma_i32_16x16x64_i8(a[ti], b[tj], acc[ti][tj], 0, 0, 0);

    __syncthreads();  // drains vmcnt -> next buffer ready; readers of cur done
    cur ^= 1;
  }
#undef STAGE

  // epilogue: D frag: col = lane&15, row = (lane>>4)*4 + i
#pragma unroll
  for (int ti = 0; ti < 4; ++ti) {
    const int row0 = brow + wm * 64 + ti * 16 + ((lane >> 4) << 2);
#pragma unroll
    for (int tj = 0; tj < 4; ++tj) {
      const int col = bcol + wn * 64 + tj * 16 + (lane & 15);
      const float bb = bdeq[col];
#pragma unroll
      for (int i = 0; i < 4; ++i) {
        out[(size_t)(row0 + i) * N_OUT + col] = (float)acc[ti][tj][i] * inv_denom + bb;
      }
    }
  }
}

extern "C" void kernel_launch(void* const* d_in, const int* in_sizes, int n_in,
                              void* d_out, int out_size, void* d_ws, size_t ws_size,
                              hipStream_t stream) {
  const float* x = (const float*)d_in[0];
  const float* w = (const float*)d_in[1];
  const float* b = (const float*)d_in[2];
  float* out = (float*)d_out;

  char* ws = (char*)d_ws;
  float* amax = (float*)ws;                             // 3 floats
  float* bdeq = (float*)(ws + 256);                     // 4 KB
  float* px   = (float*)(ws + 8192);                    // 2048 partials (8 KB)
  float* pw   = (float*)(ws + 16384 + 8192);            // 256 partials
  signed char* qw = (signed char*)(ws + 65536);         // 1 MB
  signed char* qx = (signed char*)(ws + (1 << 21));     // 16 MB

  const int NPX = 2048, NPW = 256;
  hipLaunchKernelGGL(amax_stage1, dim3(NPX), dim3(256), 0, stream, x, M_ROWS * K_DIM / 4, px);
  hipLaunchKernelGGL(amax_stage1, dim3(NPW), dim3(256), 0, stream, w, N_OUT * K_DIM / 4, pw);
  hipLaunchKernelGGL(finalize_kernel, dim3(1), dim3(256), 0, stream, px, NPX, pw, NPW, b, amax, bdeq);
  hipLaunchKernelGGL(quant_kernel, dim3(2048), dim3(256), 0, stream, x, qx, M_ROWS * K_DIM / 4, amax, 0);
  hipLaunchKernelGGL(quant_kernel, dim3(256), dim3(256), 0, stream, w, qw, N_OUT * K_DIM / 4, amax, 1);
  hipLaunchKernelGGL(gemm_kernel, dim3(128 * 8), dim3(256), 0, stream, qx, qw, amax, bdeq, out);
}

// Round 4
// 68.340 us; speedup vs baseline: 2.6893x; 1.0351x over previous
//
#include <hip/hip_runtime.h>

// AdaPT_Linear: per-tensor int8 quantized linear.
// out = (qx @ qw^T).f32 / (sa*sw) + qb.f32/sb
// x: [16384,1024] f32, w: [1024,1024] f32, b: [1024] f32, out: [16384,1024] f32

#define M_ROWS 16384
#define K_DIM  1024
#define N_OUT  1024

typedef int v4i __attribute__((ext_vector_type(4)));

__device__ __forceinline__ void gload_lds16(const void* g, void* l) {
  __builtin_amdgcn_global_load_lds(
      (const __attribute__((address_space(1))) void*)g,
      (__attribute__((address_space(3))) void*)l, 16, 0, 0);
}

__device__ __forceinline__ float block_reduce_max4(float m, float* red) {
#pragma unroll
  for (int off = 32; off > 0; off >>= 1)
    m = fmaxf(m, __shfl_down(m, off));
  const int wid = threadIdx.x >> 6, lane = threadIdx.x & 63;
  if (lane == 0) red[wid] = m;
  __syncthreads();
  float r = fmaxf(fmaxf(red[0], red[1]), fmaxf(red[2], red[3]));
  __syncthreads();
  return r;
}

__global__ void amax_stage1(const float* __restrict__ src, int n4,
                            float* __restrict__ partials) {
  __shared__ float red[4];
  float m = 0.0f;
  const int stride = gridDim.x * blockDim.x;
  for (int idx = blockIdx.x * blockDim.x + threadIdx.x; idx < n4; idx += stride) {
    float4 v = ((const float4*)src)[idx];
    m = fmaxf(m, fmaxf(fmaxf(fabsf(v.x), fabsf(v.y)), fmaxf(fabsf(v.z), fabsf(v.w))));
  }
  float r = block_reduce_max4(m, red);
  if (threadIdx.x == 0) partials[blockIdx.x] = r;
}

__global__ void finalize_kernel(const float* __restrict__ px, int npx,
                                const float* __restrict__ pw, int npw,
                                const float* __restrict__ bias,
                                float* __restrict__ amax,
                                float* __restrict__ bdeq) {
  __shared__ float red[4];
  const int tid = threadIdx.x;

  float m = 0.0f;
  for (int i = tid; i < npx; i += 256) m = fmaxf(m, px[i]);
  float rx = block_reduce_max4(m, red);

  m = 0.0f;
  for (int i = tid; i < npw; i += 256) m = fmaxf(m, pw[i]);
  float rw = block_reduce_max4(m, red);

  float4 bv = ((const float4*)bias)[tid];  // 256*4 == 1024 exactly
  m = fmaxf(fmaxf(fabsf(bv.x), fabsf(bv.y)), fmaxf(fabsf(bv.z), fabsf(bv.w)));
  float rb = block_reduce_max4(m, red);

  if (rx == 0.0f) rx = 1.0f;
  if (rw == 0.0f) rw = 1.0f;
  if (rb == 0.0f) rb = 1.0f;
  if (tid == 0) {
    amax[0] = rx;
    amax[1] = rw;
    amax[2] = rb;
  }
  const float sb = 127.0f / rb;
  float4 q;
  q.x = fminf(fmaxf(rintf(sb * bv.x), -127.0f), 127.0f) / sb;
  q.y = fminf(fmaxf(rintf(sb * bv.y), -127.0f), 127.0f) / sb;
  q.z = fminf(fmaxf(rintf(sb * bv.z), -127.0f), 127.0f) / sb;
  q.w = fminf(fmaxf(rintf(sb * bv.w), -127.0f), 127.0f) / sb;
  ((float4*)bdeq)[tid] = q;
}

__global__ void quant_kernel(const float* __restrict__ src, signed char* __restrict__ dst,
                             int n4, const float* __restrict__ amax, int slot) {
  const float s = 127.0f / amax[slot];
  const int stride = gridDim.x * blockDim.x;
  for (int idx = blockIdx.x * blockDim.x + threadIdx.x; idx < n4; idx += stride) {
    float4 v = ((const float4*)src)[idx];
    int q0 = (int)fminf(fmaxf(rintf(s * v.x), -127.0f), 127.0f);
    int q1 = (int)fminf(fmaxf(rintf(s * v.y), -127.0f), 127.0f);
    int q2 = (int)fminf(fmaxf(rintf(s * v.z), -127.0f), 127.0f);
    int q3 = (int)fminf(fmaxf(rintf(s * v.w), -127.0f), 127.0f);
    unsigned int packed = (q0 & 0xff) | ((q1 & 0xff) << 8) |
                          ((q2 & 0xff) << 16) | ((q3 & 0xff) << 24);
    ((unsigned int*)dst)[idx] = packed;
  }
}

// ---------------------------------------------------------------------------
// i8 GEMM, 256x256 tile, BK=128 i8 (128 B), 8 waves (2Mx4N), 8-phase schedule
// (T3+T4 counted vmcnt + T2 swizzle + T5 setprio). LDS 128 KiB, 1 block/CU.
// Wave->frag interleave: R(f)=wm*64+(f&3)*16+(f>>2)*128, C(g)=wn*32+(g&1)*16+(g>>1)*128
// so A-half MH is read only in phases with that MH (frees halves early).
// Stage ledger per iter j (tiles t0=2j,t1=2j+1 in buf0/buf1; t2=2j+2,t3=2j+3):
//  ph1:A11<-t1 ph2:B11<-t1 ph3:A00<-t2 ph4:B00<-t2(+vmcnt4)
//  ph5:A01<-t2 ph6:B01<-t2 ph7:A10<-t3 ph8:B10<-t3(+vmcnt4)
// Every stage-issue is >=1 barrier after the slot's last read; vmcnt(4) at
// ph4/ph8 guarantees exactly the 4 half-tiles read in the next 4 phases.
// Swizzle: LDS linear; stored col16-unit = global-unit ^ (row&7); applied on
// the pre-swizzled global source and on the ds_read address (involution).
// ---------------------------------------------------------------------------

__global__ __launch_bounds__(512, 2) void gemm_kernel(
    const signed char* __restrict__ qx, const signed char* __restrict__ qw,
    const float* __restrict__ amax, const float* __restrict__ bdeq,
    float* __restrict__ out) {
  __shared__ char lds[131072];  // A: [2][128rows*? ] 2x32KB @0; B: 2x32KB @65536

  const int tid  = threadIdx.x;
  const int w    = tid >> 6;
  const int lane = tid & 63;
  const int wm = w >> 2;   // 0..1
  const int wn = w & 3;    // 0..3
  const int fr = lane & 15;
  const int q  = lane >> 4;

  // XCD-aware swizzle (grid 256 = 8 XCDs x 32): contiguous wg per XCD
  const int bid = blockIdx.x;
  const int wg  = (bid & 7) * 32 + (bid >> 3);
  const int Mbase = (wg >> 2) * 256;
  const int Nbase = (wg & 3) * 256;

  const signed char* gA = qx + (size_t)Mbase * K_DIM;
  const signed char* gB = qw + (size_t)Nbase * K_DIM;

  // staging addressing: per wave 2 x 1KB regions (8 rows x 128B each)
  const int lrow = lane >> 3;                       // 0..7
  const int lcol = ((lane & 7) ^ lrow) << 4;        // pre-swizzled source col

  // fragment read offsets (swizzled): unit = (kk*4+q) ^ (row&7), row&7 == fr&7
  const int u0    = (q ^ (fr & 7)) << 4;            // kk=0 unit byte; kk=1: ^64
  const int aoffA = (wm * 64 + fr) * 128 + u0;
  const int aoffB = (wn * 32 + fr) * 128 + u0;

  v4i acc[8][4] = {};

  // MAT: 0=A(qx) 1=B(qw); stage one half-tile slot (2 gloads/thread)
#define STG(MAT, BUF, HALF, T)                                                 \
  do {                                                                         \
    const signed char* _gb = (MAT) ? gB : gA;                                  \
    char* _l = lds + ((MAT) ? 65536 : 0) + (BUF)*32768 + (HALF)*16384 +        \
               w * 2048;                                                       \
    size_t _ro = (size_t)((HALF)*128 + w * 16 + lrow) * K_DIM + (T)*128 + lcol;\
    gload_lds16(_gb + _ro, _l);                                                \
    gload_lds16(_gb + _ro + (size_t)8 * K_DIM, _l + 1024);                     \
  } while (0)

#define PHASE(BUF, MH, NH, STAGE_STMT, VM4)                                    \
  do {                                                                         \
    const char* _A = lds + (BUF)*32768 + (MH)*16384;                           \
    const char* _B = lds + 65536 + (BUF)*32768 + (NH)*16384;                   \
    v4i _a[4][2], _b[2][2];                                                    \
    _Pragma("unroll") for (int f = 0; f < 4; ++f) {                            \
      _a[f][0] = *(const v4i*)(_A + (aoffA + f * 2048));                       \
      _a[f][1] = *(const v4i*)(_A + ((aoffA ^ 64) + f * 2048));                \
    }                                                                          \
    _Pragma("unroll") for (int g = 0; g < 2; ++g) {                            \
      _b[g][0] = *(const v4i*)(_B + (aoffB + g * 2048));                       \
      _b[g][1] = *(const v4i*)(_B + ((aoffB ^ 64) + g * 2048));                \
    }                                                                          \
    STAGE_STMT;                                                                \
    __builtin_amdgcn_s_barrier();                                              \
    asm volatile("s_waitcnt lgkmcnt(0)" ::: "memory");                         \
    __builtin_amdgcn_sched_barrier(0);                                         \
    __builtin_amdgcn_s_setprio(1);                                             \
    _Pragma("unroll") for (int kk = 0; kk < 2; ++kk)                           \
      _Pragma("unroll") for (int f = 0; f < 4; ++f)                            \
        _Pragma("unroll") for (int g = 0; g < 2; ++g)                          \
          acc[(MH)*4 + f][(NH)*2 + g] = __builtin_amdgcn_mfma_i32_16x16x64_i8( \
              _a[f][kk], _b[g][kk], acc[(MH)*4 + f][(NH)*2 + g], 0, 0, 0);     \
    __builtin_amdgcn_s_setprio(0);                                             \
    if (VM4) { asm volatile("s_waitcnt vmcnt(4)" ::: "memory"); }              \
    __builtin_amdgcn_s_barrier();                                              \
  } while (0)

  // prologue: buf0 <- tile0 (4 halves), buf1 h0 <- tile1 (A10,B10)
  STG(0, 0, 0, 0); STG(1, 0, 0, 0);
  STG(0, 0, 1, 0); STG(1, 0, 1, 0);
  STG(0, 1, 0, 1); STG(1, 1, 0, 1);
  asm volatile("s_waitcnt vmcnt(4)" ::: "memory");  // buf0 fully landed
  __builtin_amdgcn_s_barrier();

  for (int j = 0; j < 4; ++j) {
    const int t1 = 2 * j + 1;
    const int t2 = (2 * j + 2) & 7;  // j=3: dummy re-stage of tile 0/1,
    const int t3 = (2 * j + 3) & 7;  // lands in already-consumed slots
    PHASE(0, 0, 0, STG(0, 1, 1, t1), 0);  // ph1: A11 <- t1
    PHASE(0, 0, 1, STG(1, 1, 1, t1), 0);  // ph2: B11 <- t1
    PHASE(0, 1, 0, STG(0, 0, 0, t2), 0);  // ph3: A00 <- t2
    PHASE(0, 1, 1, STG(1, 0, 0, t2), 1);  // ph4: B00 <- t2, vmcnt(4)
    PHASE(1, 0, 0, STG(0, 0, 1, t2), 0);  // ph5: A01 <- t2
    PHASE(1, 0, 1, STG(1, 0, 1, t2), 0);  // ph6: B01 <- t2
    PHASE(1, 1, 0, STG(0, 1, 0, t3), 0);  // ph7: A10 <- t3
    PHASE(1, 1, 1, STG(1, 1, 0, t3), 1);  // ph8: B10 <- t3, vmcnt(4)
  }
#undef PHASE
#undef STG

  // epilogue: D frag col = fr, row = q*4 + i
  const float inv_denom = (amax[0] * amax[1]) * (1.0f / 16129.0f);
#pragma unroll
  for (int f = 0; f < 8; ++f) {
    const int row0 = Mbase + wm * 64 + (f & 3) * 16 + (f >> 2) * 128 + q * 4;
#pragma unroll
    for (int g = 0; g < 4; ++g) {
      const int col = Nbase + wn * 32 + (g & 1) * 16 + (g >> 1) * 128 + fr;
      const float bb = bdeq[col];
#pragma unroll
      for (int i = 0; i < 4; ++i) {
        out[(size_t)(row0 + i) * N_OUT + col] = (float)acc[f][g][i] * inv_denom + bb;
      }
    }
  }
}

extern "C" void kernel_launch(void* const* d_in, const int* in_sizes, int n_in,
                              void* d_out, int out_size, void* d_ws, size_t ws_size,
                              hipStream_t stream) {
  const float* x = (const float*)d_in[0];
  const float* w = (const float*)d_in[1];
  const float* b = (const float*)d_in[2];
  float* out = (float*)d_out;

  char* ws = (char*)d_ws;
  float* amax = (float*)ws;                             // 3 floats
  float* bdeq = (float*)(ws + 256);                     // 4 KB
  float* px   = (float*)(ws + 8192);                    // 2048 partials
  float* pw   = (float*)(ws + 16384 + 8192);            // 256 partials
  signed char* qw = (signed char*)(ws + 65536);         // 1 MB
  signed char* qx = (signed char*)(ws + (1 << 21));     // 16 MB

  const int NPX = 2048, NPW = 256;
  hipLaunchKernelGGL(amax_stage1, dim3(NPX), dim3(256), 0, stream, x, M_ROWS * K_DIM / 4, px);
  hipLaunchKernelGGL(amax_stage1, dim3(NPW), dim3(256), 0, stream, w, N_OUT * K_DIM / 4, pw);
  hipLaunchKernelGGL(finalize_kernel, dim3(1), dim3(256), 0, stream, px, NPX, pw, NPW, b, amax, bdeq);
  hipLaunchKernelGGL(quant_kernel, dim3(2048), dim3(256), 0, stream, x, qx, M_ROWS * K_DIM / 4, amax, 0);
  hipLaunchKernelGGL(quant_kernel, dim3(256), dim3(256), 0, stream, w, qw, N_OUT * K_DIM / 4, amax, 1);
  hipLaunchKernelGGL(gemm_kernel, dim3(64 * 4), dim3(512), 0, stream, qx, qw, amax, bdeq, out);
}

// Round 5
// 65.619 us; speedup vs baseline: 2.8008x; 1.0415x over previous
//
#include <hip/hip_runtime.h>

// AdaPT_Linear: per-tensor int8 quantized linear.
// out = (qx @ qw^T).f32 / (sa*sw) + qb.f32/sb
// x: [16384,1024] f32, w: [1024,1024] f32, b: [1024] f32, out: [16384,1024] f32

#define M_ROWS 16384
#define K_DIM  1024
#define N_OUT  1024

typedef int v4i __attribute__((ext_vector_type(4)));

__device__ __forceinline__ void gload_lds16(const void* g, void* l) {
  __builtin_amdgcn_global_load_lds(
      (const __attribute__((address_space(1))) void*)g,
      (__attribute__((address_space(3))) void*)l, 16, 0, 0);
}

__device__ __forceinline__ float block_reduce_max4(float m, float* red) {
#pragma unroll
  for (int off = 32; off > 0; off >>= 1)
    m = fmaxf(m, __shfl_down(m, off));
  const int wid = threadIdx.x >> 6, lane = threadIdx.x & 63;
  if (lane == 0) red[wid] = m;
  __syncthreads();
  float r = fmaxf(fmaxf(red[0], red[1]), fmaxf(red[2], red[3]));
  __syncthreads();
  return r;
}

__global__ void amax_stage1(const float* __restrict__ src, int n4,
                            float* __restrict__ partials) {
  __shared__ float red[4];
  float m = 0.0f;
  const int stride = gridDim.x * blockDim.x;
  for (int idx = blockIdx.x * blockDim.x + threadIdx.x; idx < n4; idx += stride) {
    float4 v = ((const float4*)src)[idx];
    m = fmaxf(m, fmaxf(fmaxf(fabsf(v.x), fabsf(v.y)), fmaxf(fabsf(v.z), fabsf(v.w))));
  }
  float r = block_reduce_max4(m, red);
  if (threadIdx.x == 0) partials[blockIdx.x] = r;
}

__global__ void finalize_kernel(const float* __restrict__ px, int npx,
                                const float* __restrict__ pw, int npw,
                                const float* __restrict__ bias,
                                float* __restrict__ amax,
                                float* __restrict__ bdeq) {
  __shared__ float red[4];
  const int tid = threadIdx.x;

  float m = 0.0f;
  for (int i = tid; i < npx; i += 256) m = fmaxf(m, px[i]);
  float rx = block_reduce_max4(m, red);

  m = 0.0f;
  for (int i = tid; i < npw; i += 256) m = fmaxf(m, pw[i]);
  float rw = block_reduce_max4(m, red);

  float4 bv = ((const float4*)bias)[tid];  // 256*4 == 1024 exactly
  m = fmaxf(fmaxf(fabsf(bv.x), fabsf(bv.y)), fmaxf(fabsf(bv.z), fabsf(bv.w)));
  float rb = block_reduce_max4(m, red);

  if (rx == 0.0f) rx = 1.0f;
  if (rw == 0.0f) rw = 1.0f;
  if (rb == 0.0f) rb = 1.0f;
  if (tid == 0) {
    amax[0] = rx;
    amax[1] = rw;
    amax[2] = rb;
  }
  const float sb = 127.0f / rb;
  float4 q;
  q.x = fminf(fmaxf(rintf(sb * bv.x), -127.0f), 127.0f) / sb;
  q.y = fminf(fmaxf(rintf(sb * bv.y), -127.0f), 127.0f) / sb;
  q.z = fminf(fmaxf(rintf(sb * bv.z), -127.0f), 127.0f) / sb;
  q.w = fminf(fmaxf(rintf(sb * bv.w), -127.0f), 127.0f) / sb;
  ((float4*)bdeq)[tid] = q;
}

__global__ void quant_kernel(const float* __restrict__ src, signed char* __restrict__ dst,
                             int n4, const float* __restrict__ amax, int slot) {
  const float s = 127.0f / amax[slot];
  const int stride = gridDim.x * blockDim.x;
  for (int idx = blockIdx.x * blockDim.x + threadIdx.x; idx < n4; idx += stride) {
    float4 v = ((const float4*)src)[idx];
    int q0 = (int)fminf(fmaxf(rintf(s * v.x), -127.0f), 127.0f);
    int q1 = (int)fminf(fmaxf(rintf(s * v.y), -127.0f), 127.0f);
    int q2 = (int)fminf(fmaxf(rintf(s * v.z), -127.0f), 127.0f);
    int q3 = (int)fminf(fmaxf(rintf(s * v.w), -127.0f), 127.0f);
    unsigned int packed = (q0 & 0xff) | ((q1 & 0xff) << 8) |
                          ((q2 & 0xff) << 16) | ((q3 & 0xff) << 24);
    ((unsigned int*)dst)[idx] = packed;
  }
}

// ---------------------------------------------------------------------------
// i8 GEMM, 256x256 tile, BK=128 i8, 8 waves (2Mx4N), 8-phase, register-
// persistent fragments (each fragment ds_read ONCE per K-tile: 24 b128/wave
// vs 48 before). Quadrant order per buf: (0,0),(0,1),(1,1),(1,0).
//   ph1: rd A0,B0 (12)  mfma Q00 | ph2: rd B1 (4) stg A00<-t2  mfma Q01
//   ph3: rd A1 (8) stg B00<-t2  mfma Q11 | ph4: stg B01<-t2  mfma Q10 vmcnt(6)
//   ph5-8: same on buf1 (stg A01<-t2; A10,B10<-t3; B11<-t3; A11<-t3) vmcnt(8)
// vmcnt audit (2 loads/STG/thread, steady state):
//   ph4-end: outstanding 14 = [a01,a10,b10,b11,a11](prev,8... see ledger) ->
//   vmcnt(6) drains prev-iter a10,b10,b11,a11 (deadlines ph5,ph5,ph6,ph7).
//   ph8-end: outstanding 16 -> vmcnt(8) drains a00,b00,b01,a01 (deadlines
//   next ph1,ph1,ph2,ph3). Every STG issued >=1 barrier after slot's last read.
// Swizzle: LDS linear; stored 16B-unit = global-unit ^ (row&7), applied on
// pre-swizzled global source and on ds_read address (involution). T5 setprio.
// ---------------------------------------------------------------------------

__global__ __launch_bounds__(512, 2) void gemm_kernel(
    const signed char* __restrict__ qx, const signed char* __restrict__ qw,
    const float* __restrict__ amax, const float* __restrict__ bdeq,
    float* __restrict__ out) {
  __shared__ char lds[131072];  // A: 2 bufs x 32KB @0; B: same @65536

  const int tid  = threadIdx.x;
  const int w    = tid >> 6;
  const int lane = tid & 63;
  const int wm = w >> 2;   // 0..1
  const int wn = w & 3;    // 0..3
  const int fr = lane & 15;
  const int q  = lane >> 4;

  // XCD-aware swizzle (grid 256 = 8 XCDs x 32 contiguous)
  const int bid = blockIdx.x;
  const int wg  = (bid & 7) * 32 + (bid >> 3);
  const int Mbase = (wg >> 2) * 256;
  const int Nbase = (wg & 3) * 256;

  const signed char* gA = qx + (size_t)Mbase * K_DIM;
  const signed char* gB = qw + (size_t)Nbase * K_DIM;

  // staging: per wave 16 rows (2 x 8) x 128B; pre-swizzled source column
  const int lrow = lane >> 3;                  // 0..7
  const int lcol = ((lane & 7) ^ lrow) << 4;

  // fragment read offset: stored unit = (kk*4+q) ^ (row&7); kk=1 via ^64
  const int u0    = (q ^ (fr & 7)) << 4;
  const int aoffA = (wm * 64 + fr) * 128 + u0;
  const int aoffB = (wn * 32 + fr) * 128 + u0;

  v4i acc[8][4] = {};
  v4i Ar[4][2];      // current A-half fragments [f][kk]
  v4i Br[2][2][2];   // both B-halves [NH][g][kk]

#define STG(MAT, BUF, HALF, T)                                                 \
  do {                                                                         \
    const signed char* _gb = (MAT) ? gB : gA;                                  \
    char* _l = lds + ((MAT) ? 65536 : 0) + (BUF)*32768 + (HALF)*16384 +        \
               w * 2048;                                                       \
    size_t _ro = (size_t)((HALF)*128 + w * 16 + lrow) * K_DIM + (T)*128 + lcol;\
    gload_lds16(_gb + _ro, _l);                                                \
    gload_lds16(_gb + _ro + (size_t)8 * K_DIM, _l + 1024);                     \
  } while (0)

#define RD_A(BUF, MH)                                                          \
  do {                                                                         \
    const char* _A = lds + (BUF)*32768 + (MH)*16384;                           \
    _Pragma("unroll") for (int f = 0; f < 4; ++f) {                            \
      Ar[f][0] = *(const v4i*)(_A + (aoffA + f * 2048));                       \
      Ar[f][1] = *(const v4i*)(_A + ((aoffA ^ 64) + f * 2048));                \
    }                                                                          \
  } while (0)

#define RD_B(BUF, NH)                                                          \
  do {                                                                         \
    const char* _B = lds + 65536 + (BUF)*32768 + (NH)*16384;                   \
    _Pragma("unroll") for (int g = 0; g < 2; ++g) {                            \
      Br[NH][g][0] = *(const v4i*)(_B + (aoffB + g * 2048));                   \
      Br[NH][g][1] = *(const v4i*)(_B + ((aoffB ^ 64) + g * 2048));            \
    }                                                                          \
  } while (0)

  // barrier -> drain ds_reads -> MFMA quadrant (MH,NH); tail handled by caller
#define MM(MH, NH)                                                             \
  do {                                                                         \
    __builtin_amdgcn_s_barrier();                                              \
    asm volatile("s_waitcnt lgkmcnt(0)" ::: "memory");                         \
    __builtin_amdgcn_sched_barrier(0);                                         \
    __builtin_amdgcn_s_setprio(1);                                             \
    _Pragma("unroll") for (int kk = 0; kk < 2; ++kk)                           \
      _Pragma("unroll") for (int f = 0; f < 4; ++f)                            \
        _Pragma("unroll") for (int g = 0; g < 2; ++g)                          \
          acc[(MH)*4 + f][(NH)*2 + g] = __builtin_amdgcn_mfma_i32_16x16x64_i8( \
              Ar[f][kk], Br[NH][g][kk], acc[(MH)*4 + f][(NH)*2 + g], 0, 0, 0); \
    __builtin_amdgcn_s_setprio(0);                                             \
  } while (0)

#define VM(N) asm volatile("s_waitcnt vmcnt(" #N ")" ::: "memory")
#define BAR() __builtin_amdgcn_s_barrier()

  // prologue: buf0 <- t0 (a00,b00,b01,a01), buf1 <- t1 (a10,b10,b11,a11)
  STG(0, 0, 0, 0); STG(1, 0, 0, 0); STG(1, 0, 1, 0); STG(0, 0, 1, 0);
  STG(0, 1, 0, 1); STG(1, 1, 0, 1); STG(1, 1, 1, 1); STG(0, 1, 1, 1);
  VM(8);  // buf0 fully landed
  BAR();

  for (int j = 0; j < 4; ++j) {
    const int t2 = (2 * j + 2) & 7;  // j=3: dummy re-stage into consumed slots
    const int t3 = (2 * j + 3) & 7;
    // ---- buf0 ----
    RD_A(0, 0); RD_B(0, 0);                    MM(0, 0);        BAR();  // ph1
    RD_B(0, 1); STG(0, 0, 0, t2);              MM(0, 1);        BAR();  // ph2
    RD_A(0, 1); STG(1, 0, 0, t2);              MM(1, 1);        BAR();  // ph3
    STG(1, 0, 1, t2);                          MM(1, 0); VM(6); BAR();  // ph4
    // ---- buf1 ----
    RD_A(1, 0); RD_B(1, 0); STG(0, 0, 1, t2);  MM(0, 0);        BAR();  // ph5
    RD_B(1, 1); STG(0, 1, 0, t3); STG(1, 1, 0, t3); MM(0, 1);   BAR();  // ph6
    RD_A(1, 1); STG(1, 1, 1, t3);              MM(1, 1);        BAR();  // ph7
    STG(0, 1, 1, t3);                          MM(1, 0); VM(8); BAR();  // ph8
  }
#undef MM
#undef RD_A
#undef RD_B
#undef STG
#undef VM
#undef BAR

  // epilogue: D frag col = fr, row = q*4 + i
  const float inv_denom = (amax[0] * amax[1]) * (1.0f / 16129.0f);
#pragma unroll
  for (int f = 0; f < 8; ++f) {
    const int row0 = Mbase + wm * 64 + (f & 3) * 16 + (f >> 2) * 128 + q * 4;
#pragma unroll
    for (int g = 0; g < 4; ++g) {
      const int col = Nbase + wn * 32 + (g & 1) * 16 + (g >> 1) * 128 + fr;
      const float bb = bdeq[col];
#pragma unroll
      for (int i = 0; i < 4; ++i) {
        out[(size_t)(row0 + i) * N_OUT + col] = (float)acc[f][g][i] * inv_denom + bb;
      }
    }
  }
}

extern "C" void kernel_launch(void* const* d_in, const int* in_sizes, int n_in,
                              void* d_out, int out_size, void* d_ws, size_t ws_size,
                              hipStream_t stream) {
  const float* x = (const float*)d_in[0];
  const float* w = (const float*)d_in[1];
  const float* b = (const float*)d_in[2];
  float* out = (float*)d_out;

  char* ws = (char*)d_ws;
  float* amax = (float*)ws;                             // 3 floats
  float* bdeq = (float*)(ws + 256);                     // 4 KB
  float* px   = (float*)(ws + 8192);                    // 2048 partials
  float* pw   = (float*)(ws + 16384 + 8192);            // 256 partials
  signed char* qw = (signed char*)(ws + 65536);         // 1 MB
  signed char* qx = (signed char*)(ws + (1 << 21));     // 16 MB

  const int NPX = 2048, NPW = 256;
  hipLaunchKernelGGL(amax_stage1, dim3(NPX), dim3(256), 0, stream, x, M_ROWS * K_DIM / 4, px);
  hipLaunchKernelGGL(amax_stage1, dim3(NPW), dim3(256), 0, stream, w, N_OUT * K_DIM / 4, pw);
  hipLaunchKernelGGL(finalize_kernel, dim3(1), dim3(256), 0, stream, px, NPX, pw, NPW, b, amax, bdeq);
  hipLaunchKernelGGL(quant_kernel, dim3(2048), dim3(256), 0, stream, x, qx, M_ROWS * K_DIM / 4, amax, 0);
  hipLaunchKernelGGL(quant_kernel, dim3(256), dim3(256), 0, stream, w, qw, N_OUT * K_DIM / 4, amax, 1);
  hipLaunchKernelGGL(gemm_kernel, dim3(64 * 4), dim3(512), 0, stream, qx, qw, amax, bdeq, out);
}

// Round 6
// 63.202 us; speedup vs baseline: 2.9079x; 1.0382x over previous
//
#include <hip/hip_runtime.h>

// AdaPT_Linear: per-tensor int8 quantized linear.
// out = (qx @ qw^T).f32 / (sa*sw) + qb.f32/sb
// x: [16384,1024] f32, w: [1024,1024] f32, b: [1024] f32, out: [16384,1024] f32

#define M_ROWS 16384
#define K_DIM  1024
#define N_OUT  1024

typedef int v4i __attribute__((ext_vector_type(4)));

__device__ __forceinline__ void gload_lds16(const void* g, void* l) {
  __builtin_amdgcn_global_load_lds(
      (const __attribute__((address_space(1))) void*)g,
      (__attribute__((address_space(3))) void*)l, 16, 0, 0);
}

__device__ __forceinline__ float block_reduce_max4(float m, float* red) {
#pragma unroll
  for (int off = 32; off > 0; off >>= 1)
    m = fmaxf(m, __shfl_down(m, off));
  const int wid = threadIdx.x >> 6, lane = threadIdx.x & 63;
  if (lane == 0) red[wid] = m;
  __syncthreads();
  float r = fmaxf(fmaxf(red[0], red[1]), fmaxf(red[2], red[3]));
  __syncthreads();
  return r;
}

__global__ void amax_stage1(const float* __restrict__ src, int n4,
                            float* __restrict__ partials) {
  __shared__ float red[4];
  float m = 0.0f;
  const int stride = gridDim.x * blockDim.x;
  for (int idx = blockIdx.x * blockDim.x + threadIdx.x; idx < n4; idx += stride) {
    float4 v = ((const float4*)src)[idx];
    m = fmaxf(m, fmaxf(fmaxf(fabsf(v.x), fabsf(v.y)), fmaxf(fabsf(v.z), fabsf(v.w))));
  }
  float r = block_reduce_max4(m, red);
  if (threadIdx.x == 0) partials[blockIdx.x] = r;
}

__global__ void finalize_kernel(const float* __restrict__ px, int npx,
                                const float* __restrict__ pw, int npw,
                                const float* __restrict__ bias,
                                float* __restrict__ amax,
                                float* __restrict__ bdeq) {
  __shared__ float red[4];
  const int tid = threadIdx.x;

  float m = 0.0f;
  for (int i = tid; i < npx; i += 256) m = fmaxf(m, px[i]);
  float rx = block_reduce_max4(m, red);

  m = 0.0f;
  for (int i = tid; i < npw; i += 256) m = fmaxf(m, pw[i]);
  float rw = block_reduce_max4(m, red);

  float4 bv = ((const float4*)bias)[tid];  // 256*4 == 1024 exactly
  m = fmaxf(fmaxf(fabsf(bv.x), fabsf(bv.y)), fmaxf(fabsf(bv.z), fabsf(bv.w)));
  float rb = block_reduce_max4(m, red);

  if (rx == 0.0f) rx = 1.0f;
  if (rw == 0.0f) rw = 1.0f;
  if (rb == 0.0f) rb = 1.0f;
  if (tid == 0) {
    amax[0] = rx;
    amax[1] = rw;
    amax[2] = rb;
  }
  const float sb = 127.0f / rb;
  float4 q;
  q.x = fminf(fmaxf(rintf(sb * bv.x), -127.0f), 127.0f) / sb;
  q.y = fminf(fmaxf(rintf(sb * bv.y), -127.0f), 127.0f) / sb;
  q.z = fminf(fmaxf(rintf(sb * bv.z), -127.0f), 127.0f) / sb;
  q.w = fminf(fmaxf(rintf(sb * bv.w), -127.0f), 127.0f) / sb;
  ((float4*)bdeq)[tid] = q;
}

__global__ void quant_kernel(const float* __restrict__ src, signed char* __restrict__ dst,
                             int n4, const float* __restrict__ amax, int slot) {
  const float s = 127.0f / amax[slot];
  const int stride = gridDim.x * blockDim.x;
  for (int idx = blockIdx.x * blockDim.x + threadIdx.x; idx < n4; idx += stride) {
    float4 v = ((const float4*)src)[idx];
    int q0 = (int)fminf(fmaxf(rintf(s * v.x), -127.0f), 127.0f);
    int q1 = (int)fminf(fmaxf(rintf(s * v.y), -127.0f), 127.0f);
    int q2 = (int)fminf(fmaxf(rintf(s * v.z), -127.0f), 127.0f);
    int q3 = (int)fminf(fmaxf(rintf(s * v.w), -127.0f), 127.0f);
    unsigned int packed = (q0 & 0xff) | ((q1 & 0xff) << 8) |
                          ((q2 & 0xff) << 16) | ((q3 & 0xff) << 24);
    ((unsigned int*)dst)[idx] = packed;
  }
}

// ---------------------------------------------------------------------------
// i8 GEMM, 256x256 tile, BK=128 i8, 8 waves (2Mx4N), 8-phase, register-
// persistent fragments. This round: NO scheduler pins inside phases — reads
// are C++ loads, compiler emits fine-grained lgkmcnt so MFMA overlaps ds_read
// (m97 evidence). Exactly ONE barrier per phase: lgkmcnt(0)+s_barrier at
// phase end (stager may only overwrite a slot >=1 barrier after its last
// read; slot sets within a phase are disjoint — audited per phase below).
// Ledger (iter j in 0..2; buf0 holds t=2j, buf1 t=2j+1; t2=2j+2, t3=2j+3):
//  ph1: rd A0,B0           mfma Q00
//  ph2: stg A00<-t2 rd B1  mfma Q01      (A0 last read ph1)
//  ph3: stg B00<-t2 rd A1  mfma Q11      (B0 last read ph1)
//  ph4: stg B01<-t2        mfma Q10 VM(6)(B1 read ph2; drains prev-iter buf1)
//  ph5: stg A01<-t2 rd A0',B0' mfma Q00  (A1 read ph3)
//  ph6: stg A10,B10<-t3 rd B1' mfma Q01  (buf1 A0,B0 read ph5)
//  ph7: stg B11<-t3 rd A1' mfma Q11      (B1' read ph6)
//  ph8: stg A11<-t3        mfma Q10 VM(8)(A1' read ph7; drains t2->buf0)
// vmcnt audit (2 loads/STG): ph4-end outstanding 14 -> VM(6) drains prev
// a10,b10,b11,a11 (deadlines ph5,ph5,ph6,ph7). ph8-end outstanding 16 ->
// VM(8) drains a00,b00,b01,a01 (deadlines next ph1,ph1,ph2,ph3).
// Peeled j=3: no stages; ph4 VM(0) drains j2's buf1 loads; ph5-8 run
// BARRIER-FREE (no LDS writes remain) with each quadrant stored right after
// its final MFMA — spreads the 256KB/block store burst over the tail.
// Swizzle: LDS linear; stored 16B-unit = global-unit ^ (row&7) on the
// pre-swizzled source and on the ds_read address (involution).
// ---------------------------------------------------------------------------

__global__ __launch_bounds__(512, 2) void gemm_kernel(
    const signed char* __restrict__ qx, const signed char* __restrict__ qw,
    const float* __restrict__ amax, const float* __restrict__ bdeq,
    float* __restrict__ out) {
  __shared__ char lds[131072];  // A: 2 bufs x 32KB @0; B: same @65536

  const int tid  = threadIdx.x;
  const int w    = tid >> 6;
  const int lane = tid & 63;
  const int wm = w >> 2;   // 0..1
  const int wn = w & 3;    // 0..3
  const int fr = lane & 15;
  const int q  = lane >> 4;

  // XCD-aware swizzle (grid 256 = 8 XCDs x 32 contiguous)
  const int bid = blockIdx.x;
  const int wg  = (bid & 7) * 32 + (bid >> 3);
  const int Mbase = (wg >> 2) * 256;
  const int Nbase = (wg & 3) * 256;

  const signed char* gA = qx + (size_t)Mbase * K_DIM;
  const signed char* gB = qw + (size_t)Nbase * K_DIM;

  // staging: per wave 16 rows (2 x 8) x 128B; pre-swizzled source column
  const int lrow = lane >> 3;                  // 0..7
  const int lcol = ((lane & 7) ^ lrow) << 4;

  // fragment read offset: stored unit = (kk*4+q) ^ (row&7); kk=1 via ^64
  const int u0    = (q ^ (fr & 7)) << 4;
  const int aoffA = (wm * 64 + fr) * 128 + u0;
  const int aoffB = (wn * 32 + fr) * 128 + u0;

  const float inv_denom = (amax[0] * amax[1]) * (1.0f / 16129.0f);

  v4i acc[8][4] = {};
  v4i Ar[4][2];      // current A-half fragments [f][kk]
  v4i Br[2][2][2];   // both B-halves [NH][g][kk]

#define STG(MAT, BUF, HALF, T)                                                 \
  do {                                                                         \
    const signed char* _gb = (MAT) ? gB : gA;                                  \
    char* _l = lds + ((MAT) ? 65536 : 0) + (BUF)*32768 + (HALF)*16384 +        \
               w * 2048;                                                       \
    size_t _ro = (size_t)((HALF)*128 + w * 16 + lrow) * K_DIM + (T)*128 + lcol;\
    gload_lds16(_gb + _ro, _l);                                                \
    gload_lds16(_gb + _ro + (size_t)8 * K_DIM, _l + 1024);                     \
  } while (0)

#define RD_A(BUF, MH)                                                          \
  do {                                                                         \
    const char* _A = lds + (BUF)*32768 + (MH)*16384;                           \
    _Pragma("unroll") for (int f = 0; f < 4; ++f) {                            \
      Ar[f][0] = *(const v4i*)(_A + (aoffA + f * 2048));                       \
      Ar[f][1] = *(const v4i*)(_A + ((aoffA ^ 64) + f * 2048));                \
    }                                                                          \
  } while (0)

#define RD_B(BUF, NH)                                                          \
  do {                                                                         \
    const char* _B = lds + 65536 + (BUF)*32768 + (NH)*16384;                   \
    _Pragma("unroll") for (int g = 0; g < 2; ++g) {                            \
      Br[NH][g][0] = *(const v4i*)(_B + (aoffB + g * 2048));                   \
      Br[NH][g][1] = *(const v4i*)(_B + ((aoffB ^ 64) + g * 2048));            \
    }                                                                          \
  } while (0)

#define MFMA_Q(MH, NH)                                                         \
  do {                                                                         \
    _Pragma("unroll") for (int kk = 0; kk < 2; ++kk)                           \
      _Pragma("unroll") for (int f = 0; f < 4; ++f)                            \
        _Pragma("unroll") for (int g = 0; g < 2; ++g)                          \
          acc[(MH)*4 + f][(NH)*2 + g] = __builtin_amdgcn_mfma_i32_16x16x64_i8( \
              Ar[f][kk], Br[NH][g][kk], acc[(MH)*4 + f][(NH)*2 + g], 0, 0, 0); \
  } while (0)

#define STORE_Q(MH, NH)                                                        \
  do {                                                                         \
    _Pragma("unroll") for (int f = 0; f < 4; ++f) {                            \
      const int _row0 = Mbase + wm * 64 + f * 16 + (MH)*128 + q * 4;           \
      _Pragma("unroll") for (int g = 0; g < 2; ++g) {                          \
        const int _col = Nbase + wn * 32 + g * 16 + (NH)*128 + fr;             \
        const float _bb = bdeq[_col];                                          \
        _Pragma("unroll") for (int i = 0; i < 4; ++i)                          \
          out[(size_t)(_row0 + i) * N_OUT + _col] =                            \
              (float)acc[(MH)*4 + f][(NH)*2 + g][i] * inv_denom + _bb;         \
      }                                                                        \
    }                                                                          \
  } while (0)

#define VM(N) asm volatile("s_waitcnt vmcnt(" #N ")" ::: "memory")
#define ENDPH()                                                                \
  do {                                                                         \
    asm volatile("s_waitcnt lgkmcnt(0)" ::: "memory");                         \
    __builtin_amdgcn_s_barrier();                                              \
  } while (0)

  // prologue: buf0 <- t0 (a00,b00,b01,a01), buf1 <- t1 (a10,b10,b11,a11)
  STG(0, 0, 0, 0); STG(1, 0, 0, 0); STG(1, 0, 1, 0); STG(0, 0, 1, 0);
  STG(0, 1, 0, 1); STG(1, 1, 0, 1); STG(1, 1, 1, 1); STG(0, 1, 1, 1);
  VM(8);  // buf0 fully landed
  __builtin_amdgcn_s_barrier();

  for (int j = 0; j < 3; ++j) {
    const int t2 = 2 * j + 2;
    const int t3 = 2 * j + 3;
    // ---- buf0 ----
    RD_A(0, 0); RD_B(0, 0);                    MFMA_Q(0, 0);        ENDPH();
    STG(0, 0, 0, t2); RD_B(0, 1);              MFMA_Q(0, 1);        ENDPH();
    STG(1, 0, 0, t2); RD_A(0, 1);              MFMA_Q(1, 1);        ENDPH();
    STG(1, 0, 1, t2);                          MFMA_Q(1, 0); VM(6); ENDPH();
    // ---- buf1 ----
    STG(0, 0, 1, t2); RD_A(1, 0); RD_B(1, 0);  MFMA_Q(0, 0);        ENDPH();
    STG(0, 1, 0, t3); STG(1, 1, 0, t3); RD_B(1, 1); MFMA_Q(0, 1);   ENDPH();
    STG(1, 1, 1, t3); RD_A(1, 1);              MFMA_Q(1, 1);        ENDPH();
    STG(0, 1, 1, t3);                          MFMA_Q(1, 0); VM(8); ENDPH();
  }

  // ---- peeled j=3: no stages; barrier-free tail with interleaved stores ----
  RD_A(0, 0); RD_B(0, 0);  MFMA_Q(0, 0);        ENDPH();
  RD_B(0, 1);              MFMA_Q(0, 1);        ENDPH();
  RD_A(0, 1);              MFMA_Q(1, 1);        ENDPH();
                           MFMA_Q(1, 0); VM(0); ENDPH();  // buf1(t7) landed
  RD_A(1, 0); RD_B(1, 0);  MFMA_Q(0, 0);  STORE_Q(0, 0);
  RD_B(1, 1);              MFMA_Q(0, 1);  STORE_Q(0, 1);
  RD_A(1, 1);              MFMA_Q(1, 1);  STORE_Q(1, 1);
                           MFMA_Q(1, 0);  STORE_Q(1, 0);

#undef STG
#undef RD_A
#undef RD_B
#undef MFMA_Q
#undef STORE_Q
#undef VM
#undef ENDPH
}

extern "C" void kernel_launch(void* const* d_in, const int* in_sizes, int n_in,
                              void* d_out, int out_size, void* d_ws, size_t ws_size,
                              hipStream_t stream) {
  const float* x = (const float*)d_in[0];
  const float* w = (const float*)d_in[1];
  const float* b = (const float*)d_in[2];
  float* out = (float*)d_out;

  char* ws = (char*)d_ws;
  float* amax = (float*)ws;                             // 3 floats
  float* bdeq = (float*)(ws + 256);                     // 4 KB
  float* px   = (float*)(ws + 8192);                    // 2048 partials
  float* pw   = (float*)(ws + 16384 + 8192);            // 256 partials
  signed char* qw = (signed char*)(ws + 65536);         // 1 MB
  signed char* qx = (signed char*)(ws + (1 << 21));     // 16 MB

  const int NPX = 2048, NPW = 256;
  hipLaunchKernelGGL(amax_stage1, dim3(NPX), dim3(256), 0, stream, x, M_ROWS * K_DIM / 4, px);
  hipLaunchKernelGGL(amax_stage1, dim3(NPW), dim3(256), 0, stream, w, N_OUT * K_DIM / 4, pw);
  hipLaunchKernelGGL(finalize_kernel, dim3(1), dim3(256), 0, stream, px, NPX, pw, NPW, b, amax, bdeq);
  hipLaunchKernelGGL(quant_kernel, dim3(2048), dim3(256), 0, stream, x, qx, M_ROWS * K_DIM / 4, amax, 0);
  hipLaunchKernelGGL(quant_kernel, dim3(256), dim3(256), 0, stream, w, qw, N_OUT * K_DIM / 4, amax, 1);
  hipLaunchKernelGGL(gemm_kernel, dim3(64 * 4), dim3(512), 0, stream, qx, qw, amax, bdeq, out);
}